// Round 23
// baseline (220.978 us; speedup 1.0000x reference)
//
#include <hip/hip_runtime.h>

// ConvLSTM2D MI355X, R23: R22 anchor (172us) + ring import hidden under the
// second half of phase X, using COMPILER-VISIBLE system-scope loads
// (__hip_atomic_load u64 RELAXED/SYSTEM — same sc0sc1 contract as the proven
// flag poll; compiler tracks the result regs, unlike R21's fatal inline-asm
// version). Step order (t>0): X chunks 0-4 -> poll+sync -> issue import loads
// -> X chunks 5-8 -> write ring to LDS (auto-waitcnt) -> sync -> H chunks.
// All else identical to R22: 512 blk x 256 thr (2 independent blocks/CU),
// local 8-neighbor flag sync, h interior in LDS, c in regs, X staged from f32.

typedef __attribute__((ext_vector_type(8))) short short8v;
typedef __attribute__((ext_vector_type(4))) float f32x4;
typedef __attribute__((ext_vector_type(4))) unsigned int u32x4;
typedef unsigned short u16;
typedef unsigned long long u64;

#define HS 808             // shorts per kb block in H halo (101 x 16B slots)
#define HB 3200            // H halo base (shorts); X halo = [0, 3200)

__device__ __forceinline__ u16 f2bf(float x) {
    union { float f; unsigned u; } a; a.f = x;
    unsigned r = a.u + 0x7FFFu + ((a.u >> 16) & 1u);   // RNE
    return (u16)(r >> 16);
}
__device__ __forceinline__ float sigf(float x) { return 1.0f / (1.0f + __expf(-x)); }
__device__ __forceinline__ float tanhf_(float x) {
    float e = __expf(2.0f * x);
    return 1.0f - 2.0f / (e + 1.0f);
}

// ---- prep: weights -> staged layout + zero flags ----
__global__ __launch_bounds__(256)
void prep_w(const float* __restrict__ kern, const float* __restrict__ rk,
            u16* __restrict__ wt_in, u16* __restrict__ wt_rk,
            unsigned* __restrict__ flags) {
    int idx = blockIdx.x * 256 + threadIdx.x;
    if (idx < 512) flags[idx] = 0u;
    if (idx >= 82944) return;
    const float* s;
    u16* dst;
    if (idx < 9216) {
        int co = idx & 255, ckb = idx >> 8;          // 0..35 = tap*4+kb
        int tap = ckb >> 2, kb = ckb & 3;
        s = kern + (size_t)((tap << 5) + (kb << 3)) * 256 + co;
        dst = wt_in + (size_t)idx * 8;
    } else {
        int j = idx - 9216;
        int co = j & 255, rest = j >> 8;             // 0..287
        int kb = rest & 3, gc = rest >> 2;           // gc = g*18 + cc
        int g = gc / 18, cc = gc - g * 18;
        int tap = cc >> 1;
        int cib = (cc & 1) << 5;
        s = rk + (size_t)(((g * 9 + tap) << 6) + cib + (kb << 3)) * 256 + co;
        dst = wt_rk + (size_t)j * 8;
    }
    union { u16 u[8]; uint4 q; } o;
    #pragma unroll
    for (int i = 0; i < 8; ++i) o.u[i] = f2bf(s[i * 256]);
    *(uint4*)dst = o.q;
}

// stage X halo from f32 with in-register convert (no prep_x pass)
__device__ __forceinline__ void stageXf(const float* __restrict__ src,
                                        short* __restrict__ halX,
                                        int tid, int y0, int x0) {
    #pragma unroll 2
    for (int s = tid; s < 400; s += 256) {
        int pos = s >> 2, kb = s & 3;
        int hy = pos / 10, hx = pos - hy * 10;
        int gy = y0 + hy - 1, gx = x0 + hx - 1;
        union { u16 u[8]; short8v v; } o;
        o.v = (short8v){0,0,0,0,0,0,0,0};
        if ((unsigned)gy < 64u && (unsigned)gx < 64u) {
            const float* p = src + (((gy << 6) + gx) << 5) + (kb << 3);
            float4 a0 = *(const float4*)p;
            float4 a1 = *(const float4*)(p + 4);
            o.u[0] = f2bf(a0.x); o.u[1] = f2bf(a0.y);
            o.u[2] = f2bf(a0.z); o.u[3] = f2bf(a0.w);
            o.u[4] = f2bf(a1.x); o.u[5] = f2bf(a1.y);
            o.u[6] = f2bf(a1.z); o.u[7] = f2bf(a1.w);
        }
        *(short8v*)&halX[kb * 800 + pos * 8] = o.v;
    }
}

// one X chunk (16x16x32 MFMA x16), tap compile-time-agnostic
__device__ __forceinline__ void xchunk(const u16* __restrict__ wt_in,
                                       const short* __restrict__ hal,
                                       f32x4 acc[4][4], const int* aoffm,
                                       int tap, int kbl, int f) {
    const int koff = (tap / 3) * 10 + (tap % 3);
    const u16* wb = wt_in + (size_t)((((tap << 2) + kbl) << 8) + f) * 8;
    short8v bfr[4], af[4];
    #pragma unroll
    for (int n = 0; n < 4; ++n)
        bfr[n] = *(const short8v*)&wb[(size_t)n << 9];
    #pragma unroll
    for (int m = 0; m < 4; ++m)
        af[m] = *(const short8v*)&hal[kbl * 800 + (aoffm[m] + koff) * 8];
    #pragma unroll
    for (int m = 0; m < 4; ++m)
        #pragma unroll
        for (int n = 0; n < 4; ++n)
            acc[m][n] = __builtin_amdgcn_mfma_f32_16x16x32_bf16(af[m], bfr[n], acc[m][n], 0, 0, 0);
}

// ---- persistent fused conv + gates, all timesteps ----
__global__ __launch_bounds__(256, 2)
void lstm_all(const float* __restrict__ xf,   // (8,10,64,64,32) f32
              const u16* __restrict__ wt_in, const u16* __restrict__ wt_rk,
              const float* __restrict__ bias, const int* __restrict__ labels,
              u16* __restrict__ hb0, u16* __restrict__ hb1,  // h ring bufs
              float* __restrict__ out, unsigned* __restrict__ flags)
{
    // X halo @0: [kb4][100][8] (3200 shorts); H halo @3200: [kb8][HS=808]
    __shared__ short hal[HB + 8 * HS];   // 9664 shorts = 19,328 B

    const int tid  = threadIdx.x;
    const int lane = tid & 63;
    const int wq   = tid >> 6;                 // wave = f-slice 0..3
    const int b    = blockIdx.x >> 6;
    const int tile = blockIdx.x & 63;
    const int ty = tile >> 3, tx = tile & 7;
    const int y0 = ty << 3, x0 = tx << 3;
    const int g = labels[b];

    const int co_l = lane & 15;
    const int kbl  = lane >> 4;
    const int prow = (lane & 15) >> 3, pcol = lane & 7;
    const int f = (wq << 4) + co_l;

    float bv[4];
    #pragma unroll
    for (int n = 0; n < 4; ++n)
        bv[n] = bias[(g << 8) + (n << 6) + f];

    int aoffm[4];
    #pragma unroll
    for (int m = 0; m < 4; ++m)
        aoffm[m] = ((m << 1) + prow) * 10 + pcol;

    int poff[4][4], loff[4][4];
    #pragma unroll
    for (int m = 0; m < 4; ++m)
        #pragma unroll
        for (int rr = 0; rr < 4; ++rr) {
            int pf = (kbl << 2) + rr;
            int ly = (m << 1) + (pf >> 3);
            int lx = pf & 7;
            poff[m][rr] = ((((y0 + ly) << 6) + x0 + lx) << 6) + f;
            loff[m][rr] = HB + (f >> 3) * HS + ((ly + 1) * 10 + lx + 1) * 8 + (f & 7);
        }

    // ring-import unit geometry (precomputed; unit A = tid, unit B = tid+256)
    int ilA, ilB = 0;
    bool inA, inB = false;
    const bool okB = tid < 32;
    long offA = 0, offB = 0;
    {
        int posr = tid >> 3, kb = tid & 7;
        int hy, hx;
        if (posr < 10)      { hy = 0; hx = posr; }
        else if (posr < 20) { hy = 9; hx = posr - 10; }
        else { int v = posr - 20; hy = 1 + (v >> 1); hx = (v & 1) * 9; }
        int gy = y0 + hy - 1, gx = x0 + hx - 1;
        inA = (unsigned)gy < 64u && (unsigned)gx < 64u;
        offA = inA ? (long)((((gy << 6) + gx) << 6) + (kb << 3)) : 0;
        ilA = HB + kb * HS + (hy * 10 + hx) * 8;
    }
    if (okB) {
        int s = tid + 256;
        int posr = s >> 3, kb = s & 7;
        int v = posr - 20;
        int hy = 1 + (v >> 1), hx = (v & 1) * 9;
        int gy = y0 + hy - 1, gx = x0 + hx - 1;
        inB = (unsigned)gy < 64u && (unsigned)gx < 64u;
        offB = inB ? (long)((((gy << 6) + gx) << 6) + (kb << 3)) : 0;
        ilB = HB + kb * HS + (hy * 10 + hx) * 8;
    }

    float cst[4][4];
    #pragma unroll
    for (int m = 0; m < 4; ++m)
        #pragma unroll
        for (int rr = 0; rr < 4; ++rr) cst[m][rr] = 0.0f;

    const float* xsrc = xf + ((size_t)b * 10 << 17);
    float*       ob0  = out + ((size_t)b * 10 << 18);
    unsigned*    myfl = flags + (b << 6) + tile;

    // zero H halo (out-of-image ring cells stay 0 forever); stage X(0)
    for (int s = tid; s < 808; s += 256)
        *(short8v*)&hal[HB + s * 8] = (short8v){0,0,0,0,0,0,0,0};
    stageXf(xsrc, hal, tid, y0, x0);
    __syncthreads();

    for (int t = 0; t < 10; ++t) {
        u16* hw = ((t & 1) ? hb1 : hb0) + ((size_t)b << 18);   // h(t)

        f32x4 acc[4][4];
        #pragma unroll
        for (int n = 0; n < 4; ++n)
            #pragma unroll
            for (int m = 0; m < 4; ++m)
                acc[m][n] = (f32x4){bv[n], bv[n], bv[n], bv[n]};

        if (t == 0) {
            // ---- all 9 X chunks ----
            #pragma unroll 3
            for (int tap = 0; tap < 9; ++tap)
                xchunk(wt_in, hal, acc, aoffm, tap, kbl, f);
        } else {
            // ---- X chunks 0-4 (hides neighbor skew) ----
            #pragma unroll
            for (int tap = 0; tap < 5; ++tap)
                xchunk(wt_in, hal, acc, aoffm, tap, kbl, f);

            // ---- poll 8 neighbor flags (wave 0): need h(t-1) exported ----
            if (tid < 64) {
                bool valid = false; int fidx = 0;
                if (tid < 8) {
                    int kk = tid + (tid >= 4);       // 0..8 skipping center
                    int nty = ty + kk / 3 - 1, ntx = tx + kk % 3 - 1;
                    valid = (unsigned)nty < 8u && (unsigned)ntx < 8u;
                    fidx = (b << 6) + (nty << 3) + ntx;
                }
                unsigned tgt = (unsigned)t;
                int guard = 0;
                for (;;) {
                    unsigned vv = tgt;
                    if (valid)
                        vv = __hip_atomic_load(flags + fidx, __ATOMIC_RELAXED,
                                               __HIP_MEMORY_SCOPE_SYSTEM);
                    if (__all(vv >= tgt)) break;
                    if (++guard > (1 << 19)) break;
                    __builtin_amdgcn_s_sleep(2);
                }
            }
            __syncthreads();   // neighbors' h(t-1) rings globally visible

            // ---- ISSUE ring-import loads (compiler-visible system scope) ----
            const u16* hr = ((t & 1) ? hb0 : hb1) + ((size_t)b << 18);
            u64 vA0, vA1, vB0 = 0, vB1 = 0;
            {
                const u64* pa = (const u64*)(hr + offA);
                vA0 = __hip_atomic_load(pa,     __ATOMIC_RELAXED, __HIP_MEMORY_SCOPE_SYSTEM);
                vA1 = __hip_atomic_load(pa + 1, __ATOMIC_RELAXED, __HIP_MEMORY_SCOPE_SYSTEM);
            }
            if (okB) {
                const u64* pb = (const u64*)(hr + offB);
                vB0 = __hip_atomic_load(pb,     __ATOMIC_RELAXED, __HIP_MEMORY_SCOPE_SYSTEM);
                vB1 = __hip_atomic_load(pb + 1, __ATOMIC_RELAXED, __HIP_MEMORY_SCOPE_SYSTEM);
            }

            // ---- X chunks 5-8 (import latency hidden underneath) ----
            #pragma unroll
            for (int tap = 5; tap < 9; ++tap)
                xchunk(wt_in, hal, acc, aoffm, tap, kbl, f);

            // ---- write ring to LDS (compiler inserts waitcnt at use) ----
            {
                u64 a0 = inA ? vA0 : 0ull, a1 = inA ? vA1 : 0ull;
                *(u64*)&hal[ilA]     = a0;
                *(u64*)&hal[ilA + 4] = a1;
            }
            if (okB) {
                u64 b0 = inB ? vB0 : 0ull, b1 = inB ? vB1 : 0ull;
                *(u64*)&hal[ilB]     = b0;
                *(u64*)&hal[ilB + 4] = b1;
            }
            __syncthreads();   // ring in LDS

            // ---- phase H: 18 chunks ----
            #pragma unroll 3
            for (int c = 0; c < 18; ++c) {
                const int tap = c >> 1;
                const int koff = (tap / 3) * 10 + (tap % 3);
                const u16* wb = wt_rk + (size_t)(((((g * 18 + c) << 2) + kbl) << 8) + f) * 8;
                short8v bfr[4], af[4];
                #pragma unroll
                for (int n = 0; n < 4; ++n)
                    bfr[n] = *(const short8v*)&wb[(size_t)n << 9];
                const int abase = HB + (((c & 1) << 2) + kbl) * HS;
                #pragma unroll
                for (int m = 0; m < 4; ++m)
                    af[m] = *(const short8v*)&hal[abase + (aoffm[m] + koff) * 8];
                #pragma unroll
                for (int m = 0; m < 4; ++m)
                    #pragma unroll
                    for (int n = 0; n < 4; ++n)
                        acc[m][n] = __builtin_amdgcn_mfma_f32_16x16x32_bf16(af[m], bfr[n], acc[m][n], 0, 0, 0);
            }
        }
        __syncthreads();   // sync1: H-LDS (h(t-1)) reads complete

        // ---- gates + out store + h(t) interior -> LDS ----
        float* ob = ob0 + ((size_t)t << 18);
        #pragma unroll
        for (int m = 0; m < 4; ++m) {
            #pragma unroll
            for (int rr = 0; rr < 4; ++rr) {
                float zi = acc[m][0][rr], zf = acc[m][1][rr];
                float zg = acc[m][2][rr], zo = acc[m][3][rr];
                float cn = sigf(zf) * cst[m][rr] + sigf(zi) * tanhf_(zg);
                float hn = sigf(zo) * tanhf_(cn);
                cst[m][rr] = cn;
                ob[poff[m][rr]] = hn;
                hal[loff[m][rr]] = (short)f2bf(hn);
            }
        }
        __syncthreads();   // sync2: interior h(t) in LDS

        if (t < 9) {
            // ---- ring export: 28 boundary px x 8 units, sc0sc1 16B ----
            if (tid < 224) {
                int pxr = tid >> 3, kb = tid & 7;
                int dy, dx;
                if (pxr < 8)       { dy = 0; dx = pxr; }
                else if (pxr < 16) { dy = 7; dx = pxr - 8; }
                else { int v = pxr - 16; dy = 1 + (v >> 1); dx = (v & 1) * 7; }
                u32x4 v = *(const u32x4*)&hal[HB + kb * HS + ((dy + 1) * 10 + dx + 1) * 8];
                const u16* ga = hw + ((((y0 + dy) << 6) + x0 + dx) << 6) + (kb << 3);
                asm volatile("global_store_dwordx4 %0, %1, off sc0 sc1"
                             :: "v"(ga), "v"(v) : "memory");
            }
            // ---- stage X(t+1) from f32 (overlaps export latency) ----
            stageXf(xsrc + ((size_t)(t + 1) << 17), hal, tid, y0, x0);
            asm volatile("s_waitcnt vmcnt(0)" ::: "memory");  // exports drained
            __syncthreads();   // sync3: exports + X(t+1) staged
            if (tid == 0)
                __hip_atomic_fetch_add(myfl, 1u, __ATOMIC_RELAXED,
                                       __HIP_MEMORY_SCOPE_SYSTEM);
        }
    }
}

extern "C" void kernel_launch(void* const* d_in, const int* in_sizes, int n_in,
                              void* d_out, int out_size, void* d_ws, size_t ws_size,
                              hipStream_t stream)
{
    const float* x    = (const float*)d_in[0];
    const int*   lbl  = (const int*)  d_in[1];
    const float* kern = (const float*)d_in[2];
    const float* rk   = (const float*)d_in[3];
    const float* bias = (const float*)d_in[4];
    float* out = (float*)d_out;

    // ws: hb0 4.19MB | hb1 4.19MB | wt_in 0.147 | wt_rk 1.18 | flags 2KB
    u16* hb0   = (u16*)d_ws;
    u16* hb1   = hb0 + 2097152;
    u16* wt_in = hb1 + 2097152;
    u16* wt_rk = wt_in + 73728;
    unsigned* flags = (unsigned*)(wt_rk + 589824);

    hipLaunchKernelGGL(prep_w, dim3(324), dim3(256), 0, stream,
                       kern, rk, wt_in, wt_rk, flags);

    // Regular launch; co-residency guaranteed by __launch_bounds__(256, 2)
    // capacity (2 blocks/CU x 256 CUs = 512 blocks exactly; guide §1).
    hipLaunchKernelGGL(lstm_all, dim3(512), dim3(256), 0, stream,
                       x, wt_in, wt_rk, bias, lbl, hb0, hb1, out, flags);
}

// Round 24
// 177.478 us; speedup vs baseline: 1.2451x; 1.2451x over previous
//
#include <hip/hip_runtime.h>

// ConvLSTM2D MI355X, R24: R22 anchor (172us) + shortened flag-publication
// path. R22's vmcnt(0) before the flag drained the 64KB/block f32 out-stores
// + stageX loads; neighbors waited on all of it. Now: gates keep hn in regs
// (+16 VGPR), write interior-h LDS, sync2, ring export (224x16B only),
// vmcnt(0), sync3, FLAG, then out-store + stageX (drained at sync4).
// R23's import-hiding is dead (VGPR spill at 128 cap; FETCH 38->156MB).
// All else identical to R22: 512 blk x 256 thr (2 independent blocks/CU),
// local 8-neighbor flag sync, h interior in LDS, c in regs, X staged from f32.

typedef __attribute__((ext_vector_type(8))) short short8v;
typedef __attribute__((ext_vector_type(4))) float f32x4;
typedef __attribute__((ext_vector_type(4))) unsigned int u32x4;
typedef unsigned short u16;

#define HS 808             // shorts per kb block in H halo (101 x 16B slots)
#define HB 3200            // H halo base (shorts); X halo = [0, 3200)

__device__ __forceinline__ u16 f2bf(float x) {
    union { float f; unsigned u; } a; a.f = x;
    unsigned r = a.u + 0x7FFFu + ((a.u >> 16) & 1u);   // RNE
    return (u16)(r >> 16);
}
__device__ __forceinline__ float sigf(float x) { return 1.0f / (1.0f + __expf(-x)); }
__device__ __forceinline__ float tanhf_(float x) {
    float e = __expf(2.0f * x);
    return 1.0f - 2.0f / (e + 1.0f);
}

// ---- prep: weights -> staged layout + zero flags ----
__global__ __launch_bounds__(256)
void prep_w(const float* __restrict__ kern, const float* __restrict__ rk,
            u16* __restrict__ wt_in, u16* __restrict__ wt_rk,
            unsigned* __restrict__ flags) {
    int idx = blockIdx.x * 256 + threadIdx.x;
    if (idx < 512) flags[idx] = 0u;
    if (idx >= 82944) return;
    const float* s;
    u16* dst;
    if (idx < 9216) {
        int co = idx & 255, ckb = idx >> 8;          // 0..35 = tap*4+kb
        int tap = ckb >> 2, kb = ckb & 3;
        s = kern + (size_t)((tap << 5) + (kb << 3)) * 256 + co;
        dst = wt_in + (size_t)idx * 8;
    } else {
        int j = idx - 9216;
        int co = j & 255, rest = j >> 8;             // 0..287
        int kb = rest & 3, gc = rest >> 2;           // gc = g*18 + cc
        int g = gc / 18, cc = gc - g * 18;
        int tap = cc >> 1;
        int cib = (cc & 1) << 5;
        s = rk + (size_t)(((g * 9 + tap) << 6) + cib + (kb << 3)) * 256 + co;
        dst = wt_rk + (size_t)j * 8;
    }
    union { u16 u[8]; uint4 q; } o;
    #pragma unroll
    for (int i = 0; i < 8; ++i) o.u[i] = f2bf(s[i * 256]);
    *(uint4*)dst = o.q;
}

// stage X halo from f32 with in-register convert (no prep_x pass)
__device__ __forceinline__ void stageXf(const float* __restrict__ src,
                                        short* __restrict__ halX,
                                        int tid, int y0, int x0) {
    #pragma unroll 2
    for (int s = tid; s < 400; s += 256) {
        int pos = s >> 2, kb = s & 3;
        int hy = pos / 10, hx = pos - hy * 10;
        int gy = y0 + hy - 1, gx = x0 + hx - 1;
        union { u16 u[8]; short8v v; } o;
        o.v = (short8v){0,0,0,0,0,0,0,0};
        if ((unsigned)gy < 64u && (unsigned)gx < 64u) {
            const float* p = src + (((gy << 6) + gx) << 5) + (kb << 3);
            float4 a0 = *(const float4*)p;
            float4 a1 = *(const float4*)(p + 4);
            o.u[0] = f2bf(a0.x); o.u[1] = f2bf(a0.y);
            o.u[2] = f2bf(a0.z); o.u[3] = f2bf(a0.w);
            o.u[4] = f2bf(a1.x); o.u[5] = f2bf(a1.y);
            o.u[6] = f2bf(a1.z); o.u[7] = f2bf(a1.w);
        }
        *(short8v*)&halX[kb * 800 + pos * 8] = o.v;
    }
}

// ---- persistent fused conv + gates, all timesteps ----
__global__ __launch_bounds__(256, 2)
void lstm_all(const float* __restrict__ xf,   // (8,10,64,64,32) f32
              const u16* __restrict__ wt_in, const u16* __restrict__ wt_rk,
              const float* __restrict__ bias, const int* __restrict__ labels,
              u16* __restrict__ hb0, u16* __restrict__ hb1,  // h ring bufs
              float* __restrict__ out, unsigned* __restrict__ flags)
{
    // X halo @0: [kb4][100][8] (3200 shorts); H halo @3200: [kb8][HS=808]
    __shared__ short hal[HB + 8 * HS];   // 9664 shorts = 19,328 B

    const int tid  = threadIdx.x;
    const int lane = tid & 63;
    const int wq   = tid >> 6;                 // wave = f-slice 0..3
    const int b    = blockIdx.x >> 6;
    const int tile = blockIdx.x & 63;
    const int ty = tile >> 3, tx = tile & 7;
    const int y0 = ty << 3, x0 = tx << 3;
    const int g = labels[b];

    const int co_l = lane & 15;
    const int kbl  = lane >> 4;
    const int prow = (lane & 15) >> 3, pcol = lane & 7;
    const int f = (wq << 4) + co_l;

    float bv[4];
    #pragma unroll
    for (int n = 0; n < 4; ++n)
        bv[n] = bias[(g << 8) + (n << 6) + f];

    int aoffm[4];
    #pragma unroll
    for (int m = 0; m < 4; ++m)
        aoffm[m] = ((m << 1) + prow) * 10 + pcol;

    int poff[4][4], loff[4][4];
    #pragma unroll
    for (int m = 0; m < 4; ++m)
        #pragma unroll
        for (int rr = 0; rr < 4; ++rr) {
            int pf = (kbl << 2) + rr;
            int ly = (m << 1) + (pf >> 3);
            int lx = pf & 7;
            poff[m][rr] = ((((y0 + ly) << 6) + x0 + lx) << 6) + f;
            loff[m][rr] = HB + (f >> 3) * HS + ((ly + 1) * 10 + lx + 1) * 8 + (f & 7);
        }

    float cst[4][4];
    #pragma unroll
    for (int m = 0; m < 4; ++m)
        #pragma unroll
        for (int rr = 0; rr < 4; ++rr) cst[m][rr] = 0.0f;

    const float* xsrc = xf + ((size_t)b * 10 << 17);
    float*       ob0  = out + ((size_t)b * 10 << 18);
    unsigned*    myfl = flags + (b << 6) + tile;

    // zero H halo (out-of-image ring cells stay 0 forever); stage X(0)
    for (int s = tid; s < 808; s += 256)
        *(short8v*)&hal[HB + s * 8] = (short8v){0,0,0,0,0,0,0,0};
    stageXf(xsrc, hal, tid, y0, x0);
    __syncthreads();

    for (int t = 0; t < 10; ++t) {
        u16* hw = ((t & 1) ? hb1 : hb0) + ((size_t)b << 18);   // h(t)

        f32x4 acc[4][4];
        #pragma unroll
        for (int n = 0; n < 4; ++n)
            #pragma unroll
            for (int m = 0; m < 4; ++m)
                acc[m][n] = (f32x4){bv[n], bv[n], bv[n], bv[n]};

        // ---- phase X: 9 chunks (h-independent) ----
        #pragma unroll 3
        for (int tap = 0; tap < 9; ++tap) {
            const int koff = (tap / 3) * 10 + (tap % 3);
            const u16* wb = wt_in + (size_t)((((tap << 2) + kbl) << 8) + f) * 8;
            short8v bfr[4], af[4];
            #pragma unroll
            for (int n = 0; n < 4; ++n)
                bfr[n] = *(const short8v*)&wb[(size_t)n << 9];
            #pragma unroll
            for (int m = 0; m < 4; ++m)
                af[m] = *(const short8v*)&hal[kbl * 800 + (aoffm[m] + koff) * 8];
            #pragma unroll
            for (int m = 0; m < 4; ++m)
                #pragma unroll
                for (int n = 0; n < 4; ++n)
                    acc[m][n] = __builtin_amdgcn_mfma_f32_16x16x32_bf16(af[m], bfr[n], acc[m][n], 0, 0, 0);
        }

        if (t > 0) {
            // ---- poll 8 neighbor flags (wave 0): need h(t-1) exported ----
            if (tid < 64) {
                bool valid = false; int fidx = 0;
                if (tid < 8) {
                    int kk = tid + (tid >= 4);       // 0..8 skipping center
                    int nty = ty + kk / 3 - 1, ntx = tx + kk % 3 - 1;
                    valid = (unsigned)nty < 8u && (unsigned)ntx < 8u;
                    fidx = (b << 6) + (nty << 3) + ntx;
                }
                unsigned tgt = (unsigned)t;
                int guard = 0;
                for (;;) {
                    unsigned vv = tgt;
                    if (valid)
                        vv = __hip_atomic_load(flags + fidx, __ATOMIC_RELAXED,
                                               __HIP_MEMORY_SCOPE_SYSTEM);
                    if (__all(vv >= tgt)) break;
                    if (++guard > (1 << 19)) break;
                    __builtin_amdgcn_s_sleep(2);
                }
            }
            __syncthreads();   // neighbors' h(t-1) rings globally visible

            // ---- import ring h(t-1): 36 px x 8 units, sc0sc1 16B ----
            {
                const u16* hr = ((t & 1) ? hb0 : hb1) + ((size_t)b << 18);
                #pragma unroll
                for (int u = 0; u < 2; ++u) {
                    int s = tid + (u << 8);
                    if (s < 288) {
                        int posr = s >> 3, kb = s & 7;
                        int hy, hx;
                        if (posr < 10)      { hy = 0; hx = posr; }
                        else if (posr < 20) { hy = 9; hx = posr - 10; }
                        else { int v = posr - 20; hy = 1 + (v >> 1); hx = (v & 1) * 9; }
                        int gy = y0 + hy - 1, gx = x0 + hx - 1;
                        bool inb = (unsigned)gy < 64u && (unsigned)gx < 64u;
                        const u16* ga = inb ? (hr + (((gy << 6) + gx) << 6) + (kb << 3)) : hr;
                        u32x4 v;
                        asm volatile("global_load_dwordx4 %0, %1, off sc0 sc1"
                                     : "=v"(v) : "v"(ga) : "memory");
                        asm volatile("s_waitcnt vmcnt(0)" ::: "memory");
                        __builtin_amdgcn_sched_barrier(0);
                        if (!inb) v = (u32x4){0u, 0u, 0u, 0u};
                        *(u32x4*)&hal[HB + kb * HS + (hy * 10 + hx) * 8] = v;
                    }
                }
            }
            __syncthreads();   // ring in LDS

            // ---- phase H: 18 chunks ----
            #pragma unroll 3
            for (int c = 0; c < 18; ++c) {
                const int tap = c >> 1;
                const int koff = (tap / 3) * 10 + (tap % 3);
                const u16* wb = wt_rk + (size_t)(((((g * 18 + c) << 2) + kbl) << 8) + f) * 8;
                short8v bfr[4], af[4];
                #pragma unroll
                for (int n = 0; n < 4; ++n)
                    bfr[n] = *(const short8v*)&wb[(size_t)n << 9];
                const int abase = HB + (((c & 1) << 2) + kbl) * HS;
                #pragma unroll
                for (int m = 0; m < 4; ++m)
                    af[m] = *(const short8v*)&hal[abase + (aoffm[m] + koff) * 8];
                #pragma unroll
                for (int m = 0; m < 4; ++m)
                    #pragma unroll
                    for (int n = 0; n < 4; ++n)
                        acc[m][n] = __builtin_amdgcn_mfma_f32_16x16x32_bf16(af[m], bfr[n], acc[m][n], 0, 0, 0);
            }
        }
        __syncthreads();   // sync1: H-LDS (h(t-1)) reads complete

        // ---- gates: compute, keep hn in regs; interior h -> LDS only ----
        float hnv[4][4];
        #pragma unroll
        for (int m = 0; m < 4; ++m) {
            #pragma unroll
            for (int rr = 0; rr < 4; ++rr) {
                float zi = acc[m][0][rr], zf = acc[m][1][rr];
                float zg = acc[m][2][rr], zo = acc[m][3][rr];
                float cn = sigf(zf) * cst[m][rr] + sigf(zi) * tanhf_(zg);
                float hn = sigf(zo) * tanhf_(cn);
                cst[m][rr] = cn;
                hnv[m][rr] = hn;
                hal[loff[m][rr]] = (short)f2bf(hn);
            }
        }
        __syncthreads();   // sync2: interior h(t) in LDS

        float* ob = ob0 + ((size_t)t << 18);
        if (t < 9) {
            // ---- ring export FIRST (tiny: 224 x 16B), then flag ASAP ----
            if (tid < 224) {
                int pxr = tid >> 3, kb = tid & 7;
                int dy, dx;
                if (pxr < 8)       { dy = 0; dx = pxr; }
                else if (pxr < 16) { dy = 7; dx = pxr - 8; }
                else { int v = pxr - 16; dy = 1 + (v >> 1); dx = (v & 1) * 7; }
                u32x4 v = *(const u32x4*)&hal[HB + kb * HS + ((dy + 1) * 10 + dx + 1) * 8];
                const u16* ga = hw + ((((y0 + dy) << 6) + x0 + dx) << 6) + (kb << 3);
                asm volatile("global_store_dwordx4 %0, %1, off sc0 sc1"
                             :: "v"(ga), "v"(v) : "memory");
            }
            asm volatile("s_waitcnt vmcnt(0)" ::: "memory");  // exports only
            __syncthreads();   // sync3: all exports drained
            if (tid == 0)
                __hip_atomic_fetch_add(myfl, 1u, __ATOMIC_RELAXED,
                                       __HIP_MEMORY_SCOPE_SYSTEM);

            // ---- deferred out store + stage X(t+1) (fire-and-forget) ----
            #pragma unroll
            for (int m = 0; m < 4; ++m)
                #pragma unroll
                for (int rr = 0; rr < 4; ++rr)
                    ob[poff[m][rr]] = hnv[m][rr];
            stageXf(xsrc + ((size_t)(t + 1) << 17), hal, tid, y0, x0);
            __syncthreads();   // sync4: X(t+1) staged (lgkm waits inserted)
        } else {
            // last step: just the out store
            #pragma unroll
            for (int m = 0; m < 4; ++m)
                #pragma unroll
                for (int rr = 0; rr < 4; ++rr)
                    ob[poff[m][rr]] = hnv[m][rr];
        }
    }
}

extern "C" void kernel_launch(void* const* d_in, const int* in_sizes, int n_in,
                              void* d_out, int out_size, void* d_ws, size_t ws_size,
                              hipStream_t stream)
{
    const float* x    = (const float*)d_in[0];
    const int*   lbl  = (const int*)  d_in[1];
    const float* kern = (const float*)d_in[2];
    const float* rk   = (const float*)d_in[3];
    const float* bias = (const float*)d_in[4];
    float* out = (float*)d_out;

    // ws: hb0 4.19MB | hb1 4.19MB | wt_in 0.147 | wt_rk 1.18 | flags 2KB
    u16* hb0   = (u16*)d_ws;
    u16* hb1   = hb0 + 2097152;
    u16* wt_in = hb1 + 2097152;
    u16* wt_rk = wt_in + 73728;
    unsigned* flags = (unsigned*)(wt_rk + 589824);

    hipLaunchKernelGGL(prep_w, dim3(324), dim3(256), 0, stream,
                       kern, rk, wt_in, wt_rk, flags);

    // Regular launch; co-residency guaranteed by __launch_bounds__(256, 2)
    // capacity (2 blocks/CU x 256 CUs = 512 blocks exactly; guide §1).
    hipLaunchKernelGGL(lstm_all, dim3(512), dim3(256), 0, stream,
                       x, wt_in, wt_rk, bias, lbl, hb0, hb1, out, flags);
}